// Round 1
// baseline (529.664 us; speedup 1.0000x reference)
//
#include <hip/hip_runtime.h>
#include <hip/hip_bf16.h>
#include <math.h>

// Problem constants (fixed by setup_inputs)
#define BATCH 4
#define N 2048
#define D 256
#define NH 4
#define DH 64
#define TOPK 9          // k_neighbors + 1
#define NEG_BIG -1e30f

// ---------------------------------------------------------------------------
// 1) Row-normalize x -> xn  (one wave per row)
// ---------------------------------------------------------------------------
__global__ __launch_bounds__(64) void rownorm_kernel(const float* __restrict__ x,
                                                     float* __restrict__ xn) {
  int row = blockIdx.x;
  int lane = threadIdx.x;
  size_t base = (size_t)row * D + lane * 4;
  float4 v = *(const float4*)(x + base);
  float ss = v.x * v.x + v.y * v.y + v.z * v.z + v.w * v.w;
  for (int off = 32; off; off >>= 1) ss += __shfl_down(ss, off);
  ss = __shfl(ss, 0);
  float sc = 1.0f / fmaxf(sqrtf(ss), 1e-12f);
  float4 o;
  o.x = v.x * sc; o.y = v.y * sc; o.z = v.z * sc; o.w = v.w * sc;
  *(float4*)(xn + base) = o;
}

// ---------------------------------------------------------------------------
// 2) sim = A @ A^T for one batch (A = xn_b [N x D]).  fp32 VALU GEMM,
//    64x64 tile, 256 threads, 4x4 micro-tile per thread.
// ---------------------------------------------------------------------------
#define TS 64
#define TKC 32
#define LDP 68   // padded leading dim: 68*4B = 272B, 16B-aligned rows, bank-spread

__global__ __launch_bounds__(256) void simgemm_kernel(const float* __restrict__ A,
                                                      float* __restrict__ C) {
  __shared__ float As[TKC][LDP];
  __shared__ float Bs[TKC][LDP];
  int tid = threadIdx.x;
  int tx = tid & 15, ty = tid >> 4;
  int ib = blockIdx.y * TS, jb = blockIdx.x * TS;
  int lr = tid >> 2;          // 0..63 (row within tile)
  int lc = (tid & 3) * 8;     // 0,8,16,24 (col chunk)
  float acc[4][4] = {};
  for (int k0 = 0; k0 < D; k0 += TKC) {
    const float* pa = A + (size_t)(ib + lr) * D + k0 + lc;
    const float* pb = A + (size_t)(jb + lr) * D + k0 + lc;
    float4 a0 = *(const float4*)pa;
    float4 a1 = *(const float4*)(pa + 4);
    float4 b0 = *(const float4*)pb;
    float4 b1 = *(const float4*)(pb + 4);
    As[lc + 0][lr] = a0.x; As[lc + 1][lr] = a0.y; As[lc + 2][lr] = a0.z; As[lc + 3][lr] = a0.w;
    As[lc + 4][lr] = a1.x; As[lc + 5][lr] = a1.y; As[lc + 6][lr] = a1.z; As[lc + 7][lr] = a1.w;
    Bs[lc + 0][lr] = b0.x; Bs[lc + 1][lr] = b0.y; Bs[lc + 2][lr] = b0.z; Bs[lc + 3][lr] = b0.w;
    Bs[lc + 4][lr] = b1.x; Bs[lc + 5][lr] = b1.y; Bs[lc + 6][lr] = b1.z; Bs[lc + 7][lr] = b1.w;
    __syncthreads();
#pragma unroll
    for (int k = 0; k < TKC; ++k) {
      float4 av = *(const float4*)&As[k][ty * 4];
      float4 bv = *(const float4*)&Bs[k][tx * 4];
      float aa[4] = {av.x, av.y, av.z, av.w};
      float bb[4] = {bv.x, bv.y, bv.z, bv.w};
#pragma unroll
      for (int i = 0; i < 4; ++i)
#pragma unroll
        for (int j = 0; j < 4; ++j) acc[i][j] += aa[i] * bb[j];
    }
    __syncthreads();
  }
#pragma unroll
  for (int i = 0; i < 4; ++i) {
    float4 o = {acc[i][0], acc[i][1], acc[i][2], acc[i][3]};
    *(float4*)(C + (size_t)(ib + ty * 4 + i) * N + jb + tx * 4) = o;
  }
}

// ---------------------------------------------------------------------------
// 3) generic C[M x 256] = A[M x 256] @ W[256 x 256]
// ---------------------------------------------------------------------------
__global__ __launch_bounds__(256) void gemm_xw_kernel(const float* __restrict__ A,
                                                      const float* __restrict__ W,
                                                      float* __restrict__ C) {
  __shared__ float As[TKC][LDP];
  __shared__ float Bs[TKC][LDP];
  int tid = threadIdx.x;
  int tx = tid & 15, ty = tid >> 4;
  int ib = blockIdx.y * TS, jb = blockIdx.x * TS;
  int lr = tid >> 2;          // A load: row 0..63, col chunk
  int lc = (tid & 3) * 8;
  int kr = tid >> 3;          // B load: k row 0..31
  int jc = (tid & 7) * 8;     // j chunk
  float acc[4][4] = {};
  for (int k0 = 0; k0 < D; k0 += TKC) {
    const float* pa = A + (size_t)(ib + lr) * D + k0 + lc;
    float4 a0 = *(const float4*)pa;
    float4 a1 = *(const float4*)(pa + 4);
    const float* pw = W + (size_t)(k0 + kr) * D + jb + jc;
    float4 b0 = *(const float4*)pw;
    float4 b1 = *(const float4*)(pw + 4);
    As[lc + 0][lr] = a0.x; As[lc + 1][lr] = a0.y; As[lc + 2][lr] = a0.z; As[lc + 3][lr] = a0.w;
    As[lc + 4][lr] = a1.x; As[lc + 5][lr] = a1.y; As[lc + 6][lr] = a1.z; As[lc + 7][lr] = a1.w;
    *(float4*)&Bs[kr][jc] = b0;
    *(float4*)&Bs[kr][jc + 4] = b1;
    __syncthreads();
#pragma unroll
    for (int k = 0; k < TKC; ++k) {
      float4 av = *(const float4*)&As[k][ty * 4];
      float4 bv = *(const float4*)&Bs[k][tx * 4];
      float aa[4] = {av.x, av.y, av.z, av.w};
      float bb[4] = {bv.x, bv.y, bv.z, bv.w};
#pragma unroll
      for (int i = 0; i < 4; ++i)
#pragma unroll
        for (int j = 0; j < 4; ++j) acc[i][j] += aa[i] * bb[j];
    }
    __syncthreads();
  }
#pragma unroll
  for (int i = 0; i < 4; ++i) {
    float4 o = {acc[i][0], acc[i][1], acc[i][2], acc[i][3]};
    *(float4*)(C + (size_t)(ib + ty * 4 + i) * D + jb + tx * 4) = o;
  }
}

// ---------------------------------------------------------------------------
// 4) top-9 per row of sim (one wave per row).  Thread-local top-9 over a
//    strided scan, then 9 rounds of wave-wide argmax merge via LDS.
//    Branch-free insertion (no dynamic register indexing -> no scratch).
// ---------------------------------------------------------------------------
__global__ __launch_bounds__(64) void topk_kernel(const float* __restrict__ sim,
                                                  int* __restrict__ out) {
  int row = blockIdx.x;
  int lane = threadIdx.x;
  const float* srow = sim + (size_t)row * N;
  float tv[TOPK];
  int ti[TOPK];
#pragma unroll
  for (int s = 0; s < TOPK; ++s) { tv[s] = NEG_BIG; ti[s] = 0x7fffffff; }
  for (int j = lane; j < N; j += 64) {
    float vv = srow[j];
    if (vv > tv[TOPK - 1]) {
      float ntv[TOPK]; int nti[TOPK];
#pragma unroll
      for (int s = 0; s < TOPK; ++s) {
        float above = (s == 0) ? 1e38f : tv[s - 1];
        int above_i = (s == 0) ? 0 : ti[s - 1];
        if (tv[s] >= vv)      { ntv[s] = tv[s]; nti[s] = ti[s]; }
        else if (above >= vv) { ntv[s] = vv;    nti[s] = j; }
        else                  { ntv[s] = above; nti[s] = above_i; }
      }
#pragma unroll
      for (int s = 0; s < TOPK; ++s) { tv[s] = ntv[s]; ti[s] = nti[s]; }
    }
  }
  __shared__ float sv[64 * TOPK];
  __shared__ int si[64 * TOPK];
#pragma unroll
  for (int s = 0; s < TOPK; ++s) { sv[lane * TOPK + s] = tv[s]; si[lane * TOPK + s] = ti[s]; }
  __syncthreads();
  for (int r = 0; r < TOPK; ++r) {
    float bv = NEG_BIG;
    int bj = 0x7fffffff;
    int bslot = lane * TOPK;
#pragma unroll
    for (int s = 0; s < TOPK; ++s) {
      float vv = sv[lane * TOPK + s];
      int jj = si[lane * TOPK + s];
      if (vv > bv || (vv == bv && jj < bj)) { bv = vv; bj = jj; bslot = lane * TOPK + s; }
    }
    for (int off = 32; off; off >>= 1) {
      float ov = __shfl_down(bv, off);
      int oj = __shfl_down(bj, off);
      int os = __shfl_down(bslot, off);
      if (ov > bv || (ov == bv && oj < bj)) { bv = ov; bj = oj; bslot = os; }
    }
    bj = __shfl(bj, 0);
    bslot = __shfl(bslot, 0);
    if (lane == 0) {
      out[(size_t)row * TOPK + r] = bj;
      sv[bslot] = -1e38f;
    }
    __syncthreads();
  }
}

// ---------------------------------------------------------------------------
// 5) adjacency bitmask:  adj = max(A, A^T)  as bits.  mask is pre-zeroed.
// ---------------------------------------------------------------------------
__global__ void adj_kernel(const int* __restrict__ topk, unsigned* __restrict__ mask) {
  int t = blockIdx.x * blockDim.x + threadIdx.x;
  if (t >= BATCH * N * TOPK) return;
  int bn = t / TOPK;
  int b = bn / N, n = bn % N;
  int m = topk[t];
  atomicOr(&mask[((size_t)b * N + n) * (N / 32) + (m >> 5)], 1u << (m & 31));
  atomicOr(&mask[((size_t)b * N + m) * (N / 32) + (n >> 5)], 1u << (n & 31));
}

// ---------------------------------------------------------------------------
// 6) sparse masked attention: one wave per (b,n), all 4 heads.
//    Neighbors gathered from the bitmask row (~9..30 of 2048).
// ---------------------------------------------------------------------------
__global__ __launch_bounds__(64) void attn_kernel(const float* __restrict__ q,
                                                  const float* __restrict__ k,
                                                  const float* __restrict__ v,
                                                  const unsigned* __restrict__ mask,
                                                  float* __restrict__ ao) {
  __shared__ int nbr[N];
  __shared__ float w[N];
  __shared__ float sq[D];
  __shared__ int s_nn;
  int bn = blockIdx.x;
  int b = bn >> 11;  // / N
  int lane = threadIdx.x;
  if (lane == 0) s_nn = 0;
  {
    float4 qv = *(const float4*)(q + (size_t)bn * D + lane * 4);
    *(float4*)&sq[lane * 4] = qv;
  }
  __syncthreads();
  unsigned bits = mask[(size_t)bn * (N / 32) + lane];
  while (bits) {
    int bit = __ffs(bits) - 1;
    bits &= bits - 1;
    int p = atomicAdd(&s_nn, 1);
    nbr[p] = lane * 32 + bit;
  }
  __syncthreads();
  int nn = s_nn;
  const float* kb = k + (size_t)b * N * D;
  const float* vb = v + (size_t)b * N * D;
  for (int h = 0; h < NH; ++h) {
    for (int i = lane; i < nn; i += 64) {
      const float* kr = kb + (size_t)nbr[i] * D + h * DH;
      float s = 0.f;
#pragma unroll
      for (int c = 0; c < DH; ++c) s += sq[h * DH + c] * kr[c];
      w[i] = s * 0.125f;  // 1/sqrt(64)
    }
    // softmax (each lane owns its strided entries until the barrier)
    float mx = NEG_BIG;
    for (int i = lane; i < nn; i += 64) mx = fmaxf(mx, w[i]);
    for (int off = 32; off; off >>= 1) mx = fmaxf(mx, __shfl_down(mx, off));
    mx = __shfl(mx, 0);
    float ssum = 0.f;
    for (int i = lane; i < nn; i += 64) {
      float e = __expf(w[i] - mx);
      w[i] = e;
      ssum += e;
    }
    for (int off = 32; off; off >>= 1) ssum += __shfl_down(ssum, off);
    ssum = __shfl(ssum, 0);
    float inv = 1.0f / ssum;
    __syncthreads();
    float acc = 0.f;
    for (int i = 0; i < nn; ++i) acc += w[i] * vb[(size_t)nbr[i] * D + h * DH + lane];
    ao[(size_t)bn * D + h * DH + lane] = acc * inv;
    __syncthreads();
  }
}

// ---------------------------------------------------------------------------
// 7) epilogue: u = x + (proj + bo);  out = LN(u) * gamma + beta
// ---------------------------------------------------------------------------
__global__ __launch_bounds__(64) void ln_kernel(const float* __restrict__ x,
                                                const float* __restrict__ proj,
                                                const float* __restrict__ bo,
                                                const float* __restrict__ gamma,
                                                const float* __restrict__ beta,
                                                float* __restrict__ out) {
  int row = blockIdx.x;
  int lane = threadIdx.x;
  size_t base = (size_t)row * D + lane * 4;
  float4 xv = *(const float4*)(x + base);
  float4 pv = *(const float4*)(proj + base);
  float4 bv = *(const float4*)(bo + lane * 4);
  float u0 = xv.x + pv.x + bv.x, u1 = xv.y + pv.y + bv.y;
  float u2 = xv.z + pv.z + bv.z, u3 = xv.w + pv.w + bv.w;
  float s = u0 + u1 + u2 + u3;
  for (int off = 32; off; off >>= 1) s += __shfl_down(s, off);
  s = __shfl(s, 0);
  float mean = s * (1.0f / D);
  float d0 = u0 - mean, d1 = u1 - mean, d2 = u2 - mean, d3 = u3 - mean;
  float ss = d0 * d0 + d1 * d1 + d2 * d2 + d3 * d3;
  for (int off = 32; off; off >>= 1) ss += __shfl_down(ss, off);
  ss = __shfl(ss, 0);
  float rstd = rsqrtf(ss * (1.0f / D) + 1e-5f);
  float4 gv = *(const float4*)(gamma + lane * 4);
  float4 be = *(const float4*)(beta + lane * 4);
  float4 o;
  o.x = d0 * rstd * gv.x + be.x;
  o.y = d1 * rstd * gv.y + be.y;
  o.z = d2 * rstd * gv.z + be.z;
  o.w = d3 * rstd * gv.w + be.w;
  *(float4*)(out + base) = o;
}

// ---------------------------------------------------------------------------
// Launch.  Workspace layout (bytes; needs ~43 MB):
//   [ 0M.. 8M) q    (aliases xn  — xn dead after last simgemm)
//   [ 8M..16M) k    (aliases sim[0:8M] — sim dead after last topk)
//   [16M..24M) v    (aliases sim[8:16M])
//   [24M..32M) ao
//   [32M..40M) proj
//   [40M..40M+288K) topk indices
//   [41M..43M) adjacency bitmask
// ---------------------------------------------------------------------------
extern "C" void kernel_launch(void* const* d_in, const int* in_sizes, int n_in,
                              void* d_out, int out_size, void* d_ws, size_t ws_size,
                              hipStream_t stream) {
  const float* x     = (const float*)d_in[0];
  const float* Wq    = (const float*)d_in[1];
  const float* Wk    = (const float*)d_in[2];
  const float* Wv    = (const float*)d_in[3];
  const float* Wo    = (const float*)d_in[4];
  const float* bo    = (const float*)d_in[5];
  const float* gamma = (const float*)d_in[6];
  const float* beta  = (const float*)d_in[7];
  float* out = (float*)d_out;

  char* ws = (char*)d_ws;
  const size_t MB = 1024 * 1024;
  float* q    = (float*)(ws + 0 * MB);
  float* kbuf = (float*)(ws + 8 * MB);
  float* vbuf = (float*)(ws + 16 * MB);
  float* ao   = (float*)(ws + 24 * MB);
  float* proj = (float*)(ws + 32 * MB);
  int* topk   = (int*)(ws + 40 * MB);
  unsigned* mask = (unsigned*)(ws + 41 * MB);
  float* xn  = (float*)(ws + 0 * MB);  // alias q
  float* sim = (float*)(ws + 8 * MB);  // alias kbuf+vbuf (16 MB)

  rownorm_kernel<<<BATCH * N, 64, 0, stream>>>(x, xn);
  for (int b = 0; b < BATCH; ++b) {
    simgemm_kernel<<<dim3(N / TS, N / TS), 256, 0, stream>>>(xn + (size_t)b * N * D, sim);
    topk_kernel<<<N, 64, 0, stream>>>(sim, topk + (size_t)b * N * TOPK);
  }
  (void)hipMemsetAsync(mask, 0, (size_t)BATCH * N * (N / 32) * sizeof(unsigned), stream);
  adj_kernel<<<(BATCH * N * TOPK + 255) / 256, 256, 0, stream>>>(topk, mask);

  gemm_xw_kernel<<<dim3(D / TS, (BATCH * N) / TS), 256, 0, stream>>>(x, Wq, q);
  gemm_xw_kernel<<<dim3(D / TS, (BATCH * N) / TS), 256, 0, stream>>>(x, Wk, kbuf);
  gemm_xw_kernel<<<dim3(D / TS, (BATCH * N) / TS), 256, 0, stream>>>(x, Wv, vbuf);

  attn_kernel<<<BATCH * N, 64, 0, stream>>>(q, kbuf, vbuf, mask, ao);

  gemm_xw_kernel<<<dim3(D / TS, (BATCH * N) / TS), 256, 0, stream>>>(ao, Wo, proj);
  ln_kernel<<<BATCH * N, 64, 0, stream>>>(x, proj, bo, gamma, beta, out);
}

// Round 2
// 387.877 us; speedup vs baseline: 1.3655x; 1.3655x over previous
//
#include <hip/hip_runtime.h>
#include <hip/hip_bf16.h>
#include <math.h>

#define BATCH 4
#define N 2048
#define D 256
#define NH 4
#define DH 64
#define TOPK 9
#define NEG_BIG -1e30f

typedef __bf16 bf16;
typedef __bf16 bf16x8 __attribute__((ext_vector_type(8)));
typedef float f32x4 __attribute__((ext_vector_type(4)));

// chunk-map packing: 2 bits per chunk, value = source offset / 256
#define PK3(a,b,c) ((a) | ((b) << 2) | ((c) << 4))
#define PK6(a,b,c,d,e,f) ((a) | ((b) << 2) | ((c) << 4) | ((d) << 6) | ((e) << 8) | ((f) << 10))

// ---------------------------------------------------------------------------
// split rows of fp32 [rows][256] into bf16 [rows][ostride]:
//   [0..255]=hi, [256..511]=mid, optional [512..767]=lo.  Optional L2-normalize.
// ---------------------------------------------------------------------------
__global__ __launch_bounds__(64) void splitrows_kernel(const float* __restrict__ in,
                                                       bf16* __restrict__ out,
                                                       int ostride, int do_norm, int write_l) {
  int row = blockIdx.x;
  int lane = threadIdx.x;
  float4 v = *(const float4*)(in + (size_t)row * D + lane * 4);
  float sc = 1.0f;
  if (do_norm) {
    float ss = v.x * v.x + v.y * v.y + v.z * v.z + v.w * v.w;
    for (int off = 32; off; off >>= 1) ss += __shfl_down(ss, off);
    ss = __shfl(ss, 0);
    sc = 1.0f / fmaxf(sqrtf(ss), 1e-12f);
  }
  float xs[4] = {v.x * sc, v.y * sc, v.z * sc, v.w * sc};
  bf16* o = out + (size_t)row * ostride + lane * 4;
#pragma unroll
  for (int j = 0; j < 4; ++j) {
    float x = xs[j];
    bf16 h = (bf16)x;
    float r1 = x - (float)h;
    bf16 m = (bf16)r1;
    o[j] = h;
    o[256 + j] = m;
    if (write_l) {
      float r2 = r1 - (float)m;
      o[512 + j] = (bf16)r2;
    }
  }
}

// ---------------------------------------------------------------------------
// weight split+transpose: Wt[jj][0..255]=hi(W[:,j]), [256..511]=mid.
// jj 0..255 -> Wq, 256..511 -> Wk, 512..767 -> Wv, 768..1023 -> Wo.
// ---------------------------------------------------------------------------
__global__ __launch_bounds__(64) void wsplit_kernel(const float* __restrict__ W0,
                                                    const float* __restrict__ W1,
                                                    const float* __restrict__ W2,
                                                    const float* __restrict__ W3,
                                                    bf16* __restrict__ Wt) {
  int jj = blockIdx.x;
  int lane = threadIdx.x;
  const float* W = (jj < 256) ? W0 : (jj < 512) ? W1 : (jj < 768) ? W2 : W3;
  int j = jj & 255;
  bf16* dst = Wt + (size_t)jj * 512;
  for (int k = lane; k < 256; k += 64) {
    float w = W[(size_t)k * D + j];
    bf16 h = (bf16)w;
    float r = w - (float)h;
    dst[k] = h;
    dst[256 + k] = (bf16)r;
  }
}

// ---------------------------------------------------------------------------
// MFMA GEMM:  C[i][j] = sum_ch sum_k A[i][amap(ch)+k] * B[j][bmap(ch)+k]
// A: [M][lda] bf16 row-major, B: [Nc][ldb] bf16 row-major ("B^T" form).
// 128x128 tile, 256 threads = 4 waves (2x2), each wave 64x64 via 4x4 MFMA
// 16x16x32.  grid: (Nc/128, M/128, batches).  sym=1: compute bx>=by only,
// mirror-write transpose (sim is symmetric).
// ---------------------------------------------------------------------------
#define GLDS 72  // LDS row stride in bf16: 144 B, 16B-aligned

__global__ __launch_bounds__(256) void gemm_bt_kernel(const bf16* __restrict__ A,
                                                      const bf16* __restrict__ B,
                                                      float* __restrict__ C,
                                                      int lda, int ldb, int ldc,
                                                      int nsteps, int amap, int bmap,
                                                      long sA, long sB, long sC,
                                                      int sym) {
  if (sym && blockIdx.x < blockIdx.y) return;
  __shared__ bf16 As[128 * GLDS];
  __shared__ bf16 Bs[128 * GLDS];
  int tid = threadIdx.x;
  int lane = tid & 63;
  int wv = tid >> 6;
  int wm = (wv >> 1) * 64;
  int wn = (wv & 1) * 64;
  int row0 = blockIdx.y * 128;
  int col0 = blockIdx.x * 128;
  int z = blockIdx.z;
  const bf16* Ab = A + (size_t)z * sA + (size_t)row0 * lda;
  const bf16* Bb = B + (size_t)z * sB + (size_t)col0 * ldb;
  float* Cb = C + (size_t)z * sC;

  int sr = tid >> 1;          // staging row 0..127
  int sko = (tid & 1) * 32;   // staging k-offset within 64-chunk
  int fr = lane & 15;         // fragment row
  int fq = (lane >> 4) * 8;   // fragment k-offset within 32

  f32x4 acc[4][4] = {};

  for (int st = 0; st < nsteps; ++st) {
    int ch = st >> 2;
    int aoff = (((amap >> (ch * 2)) & 3) << 8) | ((st & 3) << 6);
    int boff = (((bmap >> (ch * 2)) & 3) << 8) | ((st & 3) << 6);
    const uint4* ga = (const uint4*)(Ab + (size_t)sr * lda + aoff + sko);
    const uint4* gb = (const uint4*)(Bb + (size_t)sr * ldb + boff + sko);
    uint4 a0 = ga[0], a1 = ga[1], a2 = ga[2], a3 = ga[3];
    uint4 b0 = gb[0], b1 = gb[1], b2 = gb[2], b3 = gb[3];
    __syncthreads();  // previous iteration's compute done
    uint4* wa = (uint4*)(&As[sr * GLDS + sko]);
    uint4* wb = (uint4*)(&Bs[sr * GLDS + sko]);
    wa[0] = a0; wa[1] = a1; wa[2] = a2; wa[3] = a3;
    wb[0] = b0; wb[1] = b1; wb[2] = b2; wb[3] = b3;
    __syncthreads();
#pragma unroll
    for (int ks = 0; ks < 64; ks += 32) {
      bf16x8 af[4], bfr[4];
#pragma unroll
      for (int mi = 0; mi < 4; ++mi)
        af[mi] = *(const bf16x8*)(&As[(wm + mi * 16 + fr) * GLDS + ks + fq]);
#pragma unroll
      for (int nj = 0; nj < 4; ++nj)
        bfr[nj] = *(const bf16x8*)(&Bs[(wn + nj * 16 + fr) * GLDS + ks + fq]);
#pragma unroll
      for (int mi = 0; mi < 4; ++mi)
#pragma unroll
        for (int nj = 0; nj < 4; ++nj)
          acc[mi][nj] = __builtin_amdgcn_mfma_f32_16x16x32_bf16(af[mi], bfr[nj], acc[mi][nj], 0, 0, 0);
    }
  }

  int er = (lane >> 4) * 4;  // C row base within 16x16 (row = er + reg)
  int ec = lane & 15;        // C col
#pragma unroll
  for (int mi = 0; mi < 4; ++mi)
#pragma unroll
    for (int nj = 0; nj < 4; ++nj) {
      int rb = row0 + wm + mi * 16 + er;
      int cb = col0 + wn + nj * 16 + ec;
#pragma unroll
      for (int reg = 0; reg < 4; ++reg)
        Cb[(size_t)(rb + reg) * ldc + cb] = acc[mi][nj][reg];
      if (sym && blockIdx.x != blockIdx.y) {
#pragma unroll
        for (int reg = 0; reg < 4; ++reg)
          Cb[(size_t)cb * ldc + rb + reg] = acc[mi][nj][reg];
      }
    }
}

// ---------------------------------------------------------------------------
// top-9 per row of sim (one wave per row)
// ---------------------------------------------------------------------------
__global__ __launch_bounds__(64) void topk_kernel(const float* __restrict__ sim,
                                                  int* __restrict__ out) {
  int row = blockIdx.x;
  int lane = threadIdx.x;
  const float* srow = sim + (size_t)row * N;
  float tv[TOPK];
  int ti[TOPK];
#pragma unroll
  for (int s = 0; s < TOPK; ++s) { tv[s] = NEG_BIG; ti[s] = 0x7fffffff; }
  for (int j = lane; j < N; j += 64) {
    float vv = srow[j];
    if (vv > tv[TOPK - 1]) {
      float ntv[TOPK]; int nti[TOPK];
#pragma unroll
      for (int s = 0; s < TOPK; ++s) {
        float above = (s == 0) ? 1e38f : tv[s - 1];
        int above_i = (s == 0) ? 0 : ti[s - 1];
        if (tv[s] >= vv)      { ntv[s] = tv[s]; nti[s] = ti[s]; }
        else if (above >= vv) { ntv[s] = vv;    nti[s] = j; }
        else                  { ntv[s] = above; nti[s] = above_i; }
      }
#pragma unroll
      for (int s = 0; s < TOPK; ++s) { tv[s] = ntv[s]; ti[s] = nti[s]; }
    }
  }
  __shared__ float sv[64 * TOPK];
  __shared__ int si[64 * TOPK];
#pragma unroll
  for (int s = 0; s < TOPK; ++s) { sv[lane * TOPK + s] = tv[s]; si[lane * TOPK + s] = ti[s]; }
  __syncthreads();
  for (int r = 0; r < TOPK; ++r) {
    float bv = NEG_BIG;
    int bj = 0x7fffffff;
    int bslot = lane * TOPK;
#pragma unroll
    for (int s = 0; s < TOPK; ++s) {
      float vv = sv[lane * TOPK + s];
      int jj = si[lane * TOPK + s];
      if (vv > bv || (vv == bv && jj < bj)) { bv = vv; bj = jj; bslot = lane * TOPK + s; }
    }
    for (int off = 32; off; off >>= 1) {
      float ov = __shfl_down(bv, off);
      int oj = __shfl_down(bj, off);
      int os = __shfl_down(bslot, off);
      if (ov > bv || (ov == bv && oj < bj)) { bv = ov; bj = oj; bslot = os; }
    }
    bj = __shfl(bj, 0);
    bslot = __shfl(bslot, 0);
    if (lane == 0) {
      out[(size_t)row * TOPK + r] = bj;
      sv[bslot] = -1e38f;
    }
    __syncthreads();
  }
}

// ---------------------------------------------------------------------------
// adjacency bitmask: adj = max(A, A^T) as bits (mask pre-zeroed)
// ---------------------------------------------------------------------------
__global__ void adj_kernel(const int* __restrict__ topk, unsigned* __restrict__ mask) {
  int t = blockIdx.x * blockDim.x + threadIdx.x;
  if (t >= BATCH * N * TOPK) return;
  int bn = t / TOPK;
  int b = bn / N, n = bn % N;
  int m = topk[t];
  atomicOr(&mask[((size_t)b * N + n) * (N / 32) + (m >> 5)], 1u << (m & 31));
  atomicOr(&mask[((size_t)b * N + m) * (N / 32) + (n >> 5)], 1u << (n & 31));
}

// ---------------------------------------------------------------------------
// sparse attention, one wave per (b,n), qkv packed [8192][768] = [q|k|v].
// Fast register path when nn <= 64 (always in practice), online-softmax
// fallback otherwise.  LDS only 5.3 KB -> high occupancy.
// ---------------------------------------------------------------------------
__global__ __launch_bounds__(64) void attn_kernel(const float* __restrict__ qkv,
                                                  const unsigned* __restrict__ mask,
                                                  float* __restrict__ ao) {
  __shared__ float sq[D];
  __shared__ unsigned short nbr[N];
  __shared__ int s_nn;
  int bn = blockIdx.x;
  int b = bn >> 11;
  int lane = threadIdx.x;
  if (lane == 0) s_nn = 0;
  *(float4*)&sq[lane * 4] = *(const float4*)(qkv + (size_t)bn * 768 + lane * 4);
  __syncthreads();
  unsigned bits = mask[(size_t)bn * (N / 32) + lane];
  while (bits) {
    int bit = __ffs(bits) - 1;
    bits &= bits - 1;
    int p = atomicAdd(&s_nn, 1);
    nbr[p] = (unsigned short)(lane * 32 + bit);
  }
  __syncthreads();
  int nn = s_nn;
  const float* base = qkv + (size_t)b * N * 768;
  float acc[4] = {0.f, 0.f, 0.f, 0.f};
  if (nn <= 64) {
    float s[4] = {NEG_BIG, NEG_BIG, NEG_BIG, NEG_BIG};
    if (lane < nn) {
      const float* kr = base + (size_t)nbr[lane] * 768 + 256;
#pragma unroll
      for (int h = 0; h < 4; ++h) {
        float a = 0.f;
#pragma unroll
        for (int c = 0; c < DH; c += 4) {
          float4 kk = *(const float4*)(kr + h * DH + c);
          a += sq[h * DH + c] * kk.x + sq[h * DH + c + 1] * kk.y +
               sq[h * DH + c + 2] * kk.z + sq[h * DH + c + 3] * kk.w;
        }
        s[h] = a * 0.125f;
      }
    }
    float w[4], l[4];
#pragma unroll
    for (int h = 0; h < 4; ++h) {
      float m = s[h];
      for (int off = 32; off; off >>= 1) m = fmaxf(m, __shfl_down(m, off));
      m = __shfl(m, 0);
      float e = (lane < nn) ? __expf(s[h] - m) : 0.f;
      float ls = e;
      for (int off = 32; off; off >>= 1) ls += __shfl_down(ls, off);
      l[h] = __shfl(ls, 0);
      w[h] = e;
    }
    for (int i = 0; i < nn; ++i) {
      int ji = nbr[i];
      const float* vr = base + (size_t)ji * 768 + 512;
      float w0 = __shfl(w[0], i), w1 = __shfl(w[1], i);
      float w2 = __shfl(w[2], i), w3 = __shfl(w[3], i);
      acc[0] += w0 * vr[lane];
      acc[1] += w1 * vr[64 + lane];
      acc[2] += w2 * vr[128 + lane];
      acc[3] += w3 * vr[192 + lane];
    }
#pragma unroll
    for (int h = 0; h < 4; ++h) acc[h] /= l[h];
  } else {
    float mrun[4] = {NEG_BIG, NEG_BIG, NEG_BIG, NEG_BIG};
    float lrun[4] = {0.f, 0.f, 0.f, 0.f};
    for (int i0 = 0; i0 < nn; i0 += 64) {
      int i = i0 + lane;
      float s[4] = {NEG_BIG, NEG_BIG, NEG_BIG, NEG_BIG};
      if (i < nn) {
        const float* kr = base + (size_t)nbr[i] * 768 + 256;
#pragma unroll
        for (int h = 0; h < 4; ++h) {
          float a = 0.f;
          for (int c = 0; c < DH; c += 4) {
            float4 kk = *(const float4*)(kr + h * DH + c);
            a += sq[h * DH + c] * kk.x + sq[h * DH + c + 1] * kk.y +
                 sq[h * DH + c + 2] * kk.z + sq[h * DH + c + 3] * kk.w;
          }
          s[h] = a * 0.125f;
        }
      }
      int lim = min(64, nn - i0);
#pragma unroll
      for (int h = 0; h < 4; ++h) {
        float cm = s[h];
        for (int off = 32; off; off >>= 1) cm = fmaxf(cm, __shfl_down(cm, off));
        cm = __shfl(cm, 0);
        float nm = fmaxf(mrun[h], cm);
        float e = (i < nn) ? __expf(s[h] - nm) : 0.f;
        float cs = e;
        for (int off = 32; off; off >>= 1) cs += __shfl_down(cs, off);
        cs = __shfl(cs, 0);
        float scl = (mrun[h] > NEG_BIG * 0.5f) ? __expf(mrun[h] - nm) : 0.f;
        lrun[h] = lrun[h] * scl + cs;
        acc[h] *= scl;
        mrun[h] = nm;
        for (int ii = 0; ii < lim; ++ii) {
          float wv = __shfl(e, ii);
          int ji = nbr[i0 + ii];
          acc[h] += wv * base[(size_t)ji * 768 + 512 + h * DH + lane];
        }
      }
    }
#pragma unroll
    for (int h = 0; h < 4; ++h) acc[h] /= lrun[h];
  }
#pragma unroll
  for (int h = 0; h < 4; ++h) ao[(size_t)bn * D + h * DH + lane] = acc[h];
}

// ---------------------------------------------------------------------------
// epilogue: u = x + proj + bo; out = LN(u)*gamma + beta
// ---------------------------------------------------------------------------
__global__ __launch_bounds__(64) void ln_kernel(const float* __restrict__ x,
                                                const float* __restrict__ proj,
                                                const float* __restrict__ bo,
                                                const float* __restrict__ gamma,
                                                const float* __restrict__ beta,
                                                float* __restrict__ out) {
  int row = blockIdx.x;
  int lane = threadIdx.x;
  size_t base = (size_t)row * D + lane * 4;
  float4 xv = *(const float4*)(x + base);
  float4 pv = *(const float4*)(proj + base);
  float4 bv = *(const float4*)(bo + lane * 4);
  float u0 = xv.x + pv.x + bv.x, u1 = xv.y + pv.y + bv.y;
  float u2 = xv.z + pv.z + bv.z, u3 = xv.w + pv.w + bv.w;
  float s = u0 + u1 + u2 + u3;
  for (int off = 32; off; off >>= 1) s += __shfl_down(s, off);
  s = __shfl(s, 0);
  float mean = s * (1.0f / D);
  float d0 = u0 - mean, d1 = u1 - mean, d2 = u2 - mean, d3 = u3 - mean;
  float ss = d0 * d0 + d1 * d1 + d2 * d2 + d3 * d3;
  for (int off = 32; off; off >>= 1) ss += __shfl_down(ss, off);
  ss = __shfl(ss, 0);
  float rstd = rsqrtf(ss * (1.0f / D) + 1e-5f);
  float4 gv = *(const float4*)(gamma + lane * 4);
  float4 be = *(const float4*)(beta + lane * 4);
  float4 o;
  o.x = d0 * rstd * gv.x + be.x;
  o.y = d1 * rstd * gv.y + be.y;
  o.z = d2 * rstd * gv.z + be.z;
  o.w = d3 * rstd * gv.w + be.w;
  *(float4*)(out + base) = o;
}

// ---------------------------------------------------------------------------
// Workspace layout (peak 43,286,528 B = 41.3 MiB, <= round-1-proven 43 MiB):
//   phase A (kNN):  XsN [0, 6.29M) 2-batch norm-split; sim [6.29M, 39.8M) 32MB
//   persistent:     topk [39.8M, 40.14M); mask [40.14M, 42.24M); Wt [42.24M, 43.29M)
//   phase B:        XsRaw [0, 8.39M); qkv [8.39M, 33.55M)
//   phase C:        ao [0, 8.39M); aos [8.39M, 16.78M); proj [16.78M, 25.17M)
// ---------------------------------------------------------------------------
extern "C" void kernel_launch(void* const* d_in, const int* in_sizes, int n_in,
                              void* d_out, int out_size, void* d_ws, size_t ws_size,
                              hipStream_t stream) {
  const float* x     = (const float*)d_in[0];
  const float* Wq    = (const float*)d_in[1];
  const float* Wk    = (const float*)d_in[2];
  const float* Wv    = (const float*)d_in[3];
  const float* Wo    = (const float*)d_in[4];
  const float* bo    = (const float*)d_in[5];
  const float* gamma = (const float*)d_in[6];
  const float* beta  = (const float*)d_in[7];
  float* out = (float*)d_out;

  char* ws = (char*)d_ws;
  bf16* XsN      = (bf16*)(ws);                 // 2*2048*768*2 = 6,291,456
  float* sim     = (float*)(ws + 6291456);      // 2*2048*2048*4 = 33,554,432
  int* topkb     = (int*)(ws + 39845888);       // 8192*9*4 = 294,912
  unsigned* mask = (unsigned*)(ws + 40140800);  // 4*2048*64*4 = 2,097,152
  bf16* Wt       = (bf16*)(ws + 42237952);      // 1024*512*2 = 1,048,576
  bf16* XsRaw    = (bf16*)(ws);                 // 8192*512*2 = 8,388,608
  float* qkv     = (float*)(ws + 8388608);      // 8192*768*4 = 25,165,824
  float* ao      = (float*)(ws);                // 8192*256*4 = 8,388,608
  bf16* aos      = (bf16*)(ws + 8388608);       // 8192*512*2 = 8,388,608
  float* proj    = (float*)(ws + 16777216);     // 8192*256*4 = 8,388,608

  const int AMAP_SIM = PK6(0, 1, 0, 1, 0, 2);   // h,m,h,m,h,l
  const int BMAP_SIM = PK6(0, 0, 1, 1, 2, 0);   // h,h,m,m,l,h
  const int AMAP_2T  = PK3(0, 1, 0);            // h,m,h
  const int BMAP_2T  = PK3(0, 0, 1);            // h,h,m

  // kNN: two 2-batch phases (keeps sim at 32 MB)
  for (int half = 0; half < 2; ++half) {
    splitrows_kernel<<<2 * N, 64, 0, stream>>>(x + (size_t)half * 2 * N * D, XsN, 768, 1, 1);
    gemm_bt_kernel<<<dim3(16, 16, 2), 256, 0, stream>>>(
        XsN, XsN, sim, 768, 768, N, 24, AMAP_SIM, BMAP_SIM,
        (long)N * 768, (long)N * 768, (long)N * N, 1);
    topk_kernel<<<2 * N, 64, 0, stream>>>(sim, topkb + (size_t)half * 2 * N * TOPK);
  }
  (void)hipMemsetAsync(mask, 0, (size_t)BATCH * N * (N / 32) * sizeof(unsigned), stream);
  adj_kernel<<<(BATCH * N * TOPK + 255) / 256, 256, 0, stream>>>(topkb, mask);

  // projections
  splitrows_kernel<<<BATCH * N, 64, 0, stream>>>(x, XsRaw, 512, 0, 0);
  wsplit_kernel<<<1024, 64, 0, stream>>>(Wq, Wk, Wv, Wo, Wt);
  gemm_bt_kernel<<<dim3(6, 64, 1), 256, 0, stream>>>(
      XsRaw, Wt, qkv, 512, 512, 768, 12, AMAP_2T, BMAP_2T, 0, 0, 0, 0);

  attn_kernel<<<BATCH * N, 64, 0, stream>>>(qkv, mask, ao);

  splitrows_kernel<<<BATCH * N, 64, 0, stream>>>(ao, aos, 512, 0, 0);
  gemm_bt_kernel<<<dim3(2, 64, 1), 256, 0, stream>>>(
      aos, Wt + (size_t)768 * 512, proj, 512, 512, D, 12, AMAP_2T, BMAP_2T, 0, 0, 0, 0);
  ln_kernel<<<BATCH * N, 64, 0, stream>>>(x, proj, bo, gamma, beta, out);
}

// Round 3
// 322.285 us; speedup vs baseline: 1.6435x; 1.2035x over previous
//
#include <hip/hip_runtime.h>
#include <hip/hip_bf16.h>
#include <math.h>

#define BATCH 4
#define N 2048
#define D 256
#define NH 4
#define DH 64
#define TOPK 9
#define NEG_BIG -1e30f

typedef __bf16 bf16;
typedef __bf16 bf16x8 __attribute__((ext_vector_type(8)));
typedef float f32x4 __attribute__((ext_vector_type(4)));

#define PK3(a,b,c) ((a) | ((b) << 2) | ((c) << 4))
#define PK6(a,b,c,d,e,f) ((a) | ((b) << 2) | ((c) << 4) | ((d) << 6) | ((e) << 8) | ((f) << 10))

// async global->LDS, 16B per lane.  LDS dest semantics: wave-uniform base +
// lane*16 (m104/m108) — we exploit per-lane GLOBAL addressing to implement the
// XOR swizzle on the source side.  AS casts via uintptr_t (AS3 = low 32 bits
// of the flat shared-aperture address).
__device__ __forceinline__ void async_cp16(const bf16* g, const bf16* l) {
  __builtin_amdgcn_global_load_lds(
      (const __attribute__((address_space(1))) void*)(uintptr_t)g,
      (__attribute__((address_space(3))) void*)(uintptr_t)l, 16, 0, 0);
}

// ---------------------------------------------------------------------------
// split rows of fp32 [rows][256] into bf16 [rows][ostride]:
//   [0..255]=hi, [256..511]=mid, optional [512..767]=lo.  Optional L2-norm.
// ---------------------------------------------------------------------------
__global__ __launch_bounds__(64) void splitrows_kernel(const float* __restrict__ in,
                                                       bf16* __restrict__ out,
                                                       int ostride, int do_norm, int write_l) {
  int row = blockIdx.x;
  int lane = threadIdx.x;
  float4 v = *(const float4*)(in + (size_t)row * D + lane * 4);
  float sc = 1.0f;
  if (do_norm) {
    float ss = v.x * v.x + v.y * v.y + v.z * v.z + v.w * v.w;
    for (int off = 32; off; off >>= 1) ss += __shfl_down(ss, off);
    ss = __shfl(ss, 0);
    sc = 1.0f / fmaxf(sqrtf(ss), 1e-12f);
  }
  float xs[4] = {v.x * sc, v.y * sc, v.z * sc, v.w * sc};
  bf16* o = out + (size_t)row * ostride + lane * 4;
#pragma unroll
  for (int j = 0; j < 4; ++j) {
    float x = xs[j];
    bf16 h = (bf16)x;
    float r1 = x - (float)h;
    bf16 m = (bf16)r1;
    o[j] = h;
    o[256 + j] = m;
    if (write_l) {
      float r2 = r1 - (float)m;
      o[512 + j] = (bf16)r2;
    }
  }
}

// ---------------------------------------------------------------------------
// weight split+transpose: Wt[jj][0..255]=hi(W[:,j]), [256..511]=mid.
// ---------------------------------------------------------------------------
__global__ __launch_bounds__(64) void wsplit_kernel(const float* __restrict__ W0,
                                                    const float* __restrict__ W1,
                                                    const float* __restrict__ W2,
                                                    const float* __restrict__ W3,
                                                    bf16* __restrict__ Wt) {
  int jj = blockIdx.x;
  int lane = threadIdx.x;
  const float* W = (jj < 256) ? W0 : (jj < 512) ? W1 : (jj < 768) ? W2 : W3;
  int j = jj & 255;
  bf16* dst = Wt + (size_t)jj * 512;
  for (int k = lane; k < 256; k += 64) {
    float w = W[(size_t)k * D + j];
    bf16 h = (bf16)w;
    float r = w - (float)h;
    dst[k] = h;
    dst[256 + k] = (bf16)r;
  }
}

// ---------------------------------------------------------------------------
// MFMA GEMM (m97-style):  C[i][j] = sum_ch sum_k A[i][amap+k]*B[j][bmap+k]
// 128x128 tile, 4 waves, global_load_lds staging into [128][64] bf16 LDS with
// 16B-granule XOR swizzle (granule ^= row&7) -> conflict-free ds_read_b128.
// sym=1: upper-triangular blocks only, mirror-write (sim symmetric).
// ---------------------------------------------------------------------------
__global__ __launch_bounds__(256) void gemm_bt_kernel(const bf16* __restrict__ A,
                                                      const bf16* __restrict__ B,
                                                      float* __restrict__ C,
                                                      int lda, int ldb, int ldc,
                                                      int nsteps, int amap, int bmap,
                                                      long sA, long sB, long sC,
                                                      int sym) {
  if (sym && blockIdx.x < blockIdx.y) return;
  __shared__ bf16 As[128 * 64];
  __shared__ bf16 Bs[128 * 64];
  int tid = threadIdx.x;
  int lane = tid & 63;
  int wv = tid >> 6;
  int wm = (wv >> 1) * 64;
  int wn = (wv & 1) * 64;
  int row0 = blockIdx.y * 128;
  int col0 = blockIdx.x * 128;
  int z = blockIdx.z;
  const bf16* Ab = A + (size_t)z * sA + (size_t)row0 * lda;
  const bf16* Bb = B + (size_t)z * sB + (size_t)col0 * ldb;
  float* Cb = C + (size_t)z * sC;

  // staging geometry: instr q in 0..3, thread covers LDS slot q*256+tid
  // (row = slot/8, granule = slot%8); fetches global granule (g ^ (row&7)).
  int rbase = tid >> 3;                 // 0..31
  int gperm = (tid & 7) ^ (rbase & 7);  // logical granule for this lane
  const bf16* ga0 = Ab + (size_t)rbase * lda + gperm * 8;
  const bf16* gb0 = Bb + (size_t)rbase * ldb + gperm * 8;
  const bf16* la0 = As + (size_t)tid * 8;  // slot*16 bytes
  const bf16* lb0 = Bs + (size_t)tid * 8;

  int fr = lane & 15;
  int fq = (lane >> 4) * 8;

  f32x4 acc[4][4] = {};

  for (int st = 0; st < nsteps; ++st) {
    int ch = st >> 2;
    int aoff = (((amap >> (ch * 2)) & 3) << 8) | ((st & 3) << 6);
    int boff = (((bmap >> (ch * 2)) & 3) << 8) | ((st & 3) << 6);
#pragma unroll
    for (int q = 0; q < 4; ++q)
      async_cp16(ga0 + (size_t)q * 32 * lda + aoff, la0 + q * 2048);
#pragma unroll
    for (int q = 0; q < 4; ++q)
      async_cp16(gb0 + (size_t)q * 32 * ldb + boff, lb0 + q * 2048);
    __syncthreads();  // drains vmcnt -> staged data visible
#pragma unroll
    for (int ks = 0; ks < 64; ks += 32) {
      bf16x8 af[4], bfr[4];
#pragma unroll
      for (int mi = 0; mi < 4; ++mi) {
        int r = wm + mi * 16 + fr;
        int G = (ks + fq) >> 3;
        af[mi] = *(const bf16x8*)&As[r * 64 + ((G ^ (r & 7)) << 3)];
      }
#pragma unroll
      for (int nj = 0; nj < 4; ++nj) {
        int r = wn + nj * 16 + fr;
        int G = (ks + fq) >> 3;
        bfr[nj] = *(const bf16x8*)&Bs[r * 64 + ((G ^ (r & 7)) << 3)];
      }
#pragma unroll
      for (int mi = 0; mi < 4; ++mi)
#pragma unroll
        for (int nj = 0; nj < 4; ++nj)
          acc[mi][nj] = __builtin_amdgcn_mfma_f32_16x16x32_bf16(af[mi], bfr[nj], acc[mi][nj], 0, 0, 0);
    }
    __syncthreads();  // compute done before next st overwrites LDS
  }

  int er = (lane >> 4) * 4;
  int ec = lane & 15;
#pragma unroll
  for (int mi = 0; mi < 4; ++mi)
#pragma unroll
    for (int nj = 0; nj < 4; ++nj) {
      int rb = row0 + wm + mi * 16 + er;
      int cb = col0 + wn + nj * 16 + ec;
#pragma unroll
      for (int reg = 0; reg < 4; ++reg)
        Cb[(size_t)(rb + reg) * ldc + cb] = acc[mi][nj][reg];
      if (sym && blockIdx.x != blockIdx.y) {
#pragma unroll
        for (int reg = 0; reg < 4; ++reg)
          Cb[(size_t)cb * ldc + rb + reg] = acc[mi][nj][reg];
      }
    }
}

// ---------------------------------------------------------------------------
// top-9 per row of sim (one wave per row)
// ---------------------------------------------------------------------------
__global__ __launch_bounds__(64) void topk_kernel(const float* __restrict__ sim,
                                                  int* __restrict__ out) {
  int row = blockIdx.x;
  int lane = threadIdx.x;
  const float* srow = sim + (size_t)row * N;
  float tv[TOPK];
  int ti[TOPK];
#pragma unroll
  for (int s = 0; s < TOPK; ++s) { tv[s] = NEG_BIG; ti[s] = 0x7fffffff; }
  for (int j = lane; j < N; j += 64) {
    float vv = srow[j];
    if (vv > tv[TOPK - 1]) {
      float ntv[TOPK]; int nti[TOPK];
#pragma unroll
      for (int s = 0; s < TOPK; ++s) {
        float above = (s == 0) ? 1e38f : tv[s - 1];
        int above_i = (s == 0) ? 0 : ti[s - 1];
        if (tv[s] >= vv)      { ntv[s] = tv[s]; nti[s] = ti[s]; }
        else if (above >= vv) { ntv[s] = vv;    nti[s] = j; }
        else                  { ntv[s] = above; nti[s] = above_i; }
      }
#pragma unroll
      for (int s = 0; s < TOPK; ++s) { tv[s] = ntv[s]; ti[s] = nti[s]; }
    }
  }
  __shared__ float sv[64 * TOPK];
  __shared__ int si[64 * TOPK];
#pragma unroll
  for (int s = 0; s < TOPK; ++s) { sv[lane * TOPK + s] = tv[s]; si[lane * TOPK + s] = ti[s]; }
  __syncthreads();
  for (int r = 0; r < TOPK; ++r) {
    float bv = NEG_BIG;
    int bj = 0x7fffffff;
    int bslot = lane * TOPK;
#pragma unroll
    for (int s = 0; s < TOPK; ++s) {
      float vv = sv[lane * TOPK + s];
      int jj = si[lane * TOPK + s];
      if (vv > bv || (vv == bv && jj < bj)) { bv = vv; bj = jj; bslot = lane * TOPK + s; }
    }
    for (int off = 32; off; off >>= 1) {
      float ov = __shfl_down(bv, off);
      int oj = __shfl_down(bj, off);
      int os = __shfl_down(bslot, off);
      if (ov > bv || (ov == bv && oj < bj)) { bv = ov; bj = oj; bslot = os; }
    }
    bj = __shfl(bj, 0);
    bslot = __shfl(bslot, 0);
    if (lane == 0) {
      out[(size_t)row * TOPK + r] = bj;
      sv[bslot] = -1e38f;
    }
    __syncthreads();
  }
}

// ---------------------------------------------------------------------------
// adjacency bitmask (mask pre-zeroed)
// ---------------------------------------------------------------------------
__global__ void adj_kernel(const int* __restrict__ topk, unsigned* __restrict__ mask) {
  int t = blockIdx.x * blockDim.x + threadIdx.x;
  if (t >= BATCH * N * TOPK) return;
  int bn = t / TOPK;
  int b = bn / N, n = bn % N;
  int m = topk[t];
  atomicOr(&mask[((size_t)b * N + n) * (N / 32) + (m >> 5)], 1u << (m & 31));
  atomicOr(&mask[((size_t)b * N + m) * (N / 32) + (n >> 5)], 1u << (n & 31));
}

// ---------------------------------------------------------------------------
// sparse attention: 256 threads = 4 waves, one (b,n) row per wave.
// qkv packed [8192][768] = [q|k|v].  Fast register path nn<=64 (always in
// practice); rare nn>64 handled by two-pass score recompute (low reg cost).
// ---------------------------------------------------------------------------
__global__ __launch_bounds__(256) void attn_kernel(const float* __restrict__ qkv,
                                                   const unsigned* __restrict__ mask,
                                                   float* __restrict__ ao) {
  __shared__ float sq[4][256];
  __shared__ unsigned short nbr[4][2048];
  __shared__ int s_nn[4];
  int wv = threadIdx.x >> 6;
  int lane = threadIdx.x & 63;
  int bn = blockIdx.x * 4 + wv;
  int b = bn >> 11;
  if (lane == 0) s_nn[wv] = 0;
  *(float4*)&sq[wv][lane * 4] = *(const float4*)(qkv + (size_t)bn * 768 + lane * 4);
  __syncthreads();
  unsigned bits = mask[(size_t)bn * (N / 32) + lane];
  while (bits) {
    int bit = __ffs(bits) - 1;
    bits &= bits - 1;
    int p = atomicAdd(&s_nn[wv], 1);
    nbr[wv][p] = (unsigned short)(lane * 32 + bit);
  }
  __syncthreads();
  int nn = s_nn[wv];
  const float* base = qkv + (size_t)b * N * 768;

  float acc[4] = {0.f, 0.f, 0.f, 0.f};

  auto score4 = [&](int j, float* s) {
    const float* kr = base + (size_t)j * 768 + 256;
#pragma unroll
    for (int h = 0; h < 4; ++h) {
      float a = 0.f;
#pragma unroll
      for (int c = 0; c < DH; c += 4) {
        float4 kk = *(const float4*)(kr + h * DH + c);
        a += sq[wv][h * DH + c] * kk.x + sq[wv][h * DH + c + 1] * kk.y +
             sq[wv][h * DH + c + 2] * kk.z + sq[wv][h * DH + c + 3] * kk.w;
      }
      s[h] = a * 0.125f;
    }
  };

  if (nn <= 64) {
    float s[4] = {NEG_BIG, NEG_BIG, NEG_BIG, NEG_BIG};
    if (lane < nn) score4(nbr[wv][lane], s);
    float w[4], l[4];
#pragma unroll
    for (int h = 0; h < 4; ++h) {
      float m = s[h];
      for (int off = 32; off; off >>= 1) m = fmaxf(m, __shfl_down(m, off));
      m = __shfl(m, 0);
      float e = (lane < nn) ? __expf(s[h] - m) : 0.f;
      float ls = e;
      for (int off = 32; off; off >>= 1) ls += __shfl_down(ls, off);
      l[h] = __shfl(ls, 0);
      w[h] = e;
    }
    int i = 0;
    for (; i + 4 <= nn; i += 4) {
      int j0 = nbr[wv][i + 0], j1 = nbr[wv][i + 1];
      int j2 = nbr[wv][i + 2], j3 = nbr[wv][i + 3];
      const float* p0 = base + (size_t)j0 * 768 + 512;
      const float* p1 = base + (size_t)j1 * 768 + 512;
      const float* p2 = base + (size_t)j2 * 768 + 512;
      const float* p3 = base + (size_t)j3 * 768 + 512;
#pragma unroll
      for (int h = 0; h < 4; ++h) {
        float v0 = p0[h * DH + lane], v1 = p1[h * DH + lane];
        float v2 = p2[h * DH + lane], v3 = p3[h * DH + lane];
        acc[h] += __shfl(w[h], i + 0) * v0 + __shfl(w[h], i + 1) * v1 +
                  __shfl(w[h], i + 2) * v2 + __shfl(w[h], i + 3) * v3;
      }
    }
    for (; i < nn; ++i) {
      const float* p0 = base + (size_t)nbr[wv][i] * 768 + 512;
#pragma unroll
      for (int h = 0; h < 4; ++h) acc[h] += __shfl(w[h], i) * p0[h * DH + lane];
    }
#pragma unroll
    for (int h = 0; h < 4; ++h) acc[h] /= l[h];
  } else {
    // two-pass recompute (rare): pass 1 = global max, pass 2 = sum + PV
    float m[4] = {NEG_BIG, NEG_BIG, NEG_BIG, NEG_BIG};
    for (int i0 = 0; i0 < nn; i0 += 64) {
      float s[4] = {NEG_BIG, NEG_BIG, NEG_BIG, NEG_BIG};
      if (i0 + lane < nn) score4(nbr[wv][i0 + lane], s);
#pragma unroll
      for (int h = 0; h < 4; ++h) m[h] = fmaxf(m[h], s[h]);
    }
#pragma unroll
    for (int h = 0; h < 4; ++h) {
      for (int off = 32; off; off >>= 1) m[h] = fmaxf(m[h], __shfl_down(m[h], off));
      m[h] = __shfl(m[h], 0);
    }
    float l[4] = {0.f, 0.f, 0.f, 0.f};
    for (int i0 = 0; i0 < nn; i0 += 64) {
      float s[4] = {NEG_BIG, NEG_BIG, NEG_BIG, NEG_BIG};
      if (i0 + lane < nn) score4(nbr[wv][i0 + lane], s);
      float e[4];
#pragma unroll
      for (int h = 0; h < 4; ++h) {
        e[h] = (i0 + lane < nn) ? __expf(s[h] - m[h]) : 0.f;
        float ls = e[h];
        for (int off = 32; off; off >>= 1) ls += __shfl_down(ls, off);
        l[h] += __shfl(ls, 0);
      }
      int lim = min(64, nn - i0);
      for (int ii = 0; ii < lim; ++ii) {
        const float* p0 = base + (size_t)nbr[wv][i0 + ii] * 768 + 512;
#pragma unroll
        for (int h = 0; h < 4; ++h) acc[h] += __shfl(e[h], ii) * p0[h * DH + lane];
      }
    }
#pragma unroll
    for (int h = 0; h < 4; ++h) acc[h] /= l[h];
  }
#pragma unroll
  for (int h = 0; h < 4; ++h) ao[(size_t)bn * D + h * DH + lane] = acc[h];
}

// ---------------------------------------------------------------------------
// epilogue: u = x + proj + bo; out = LN(u)*gamma + beta
// ---------------------------------------------------------------------------
__global__ __launch_bounds__(64) void ln_kernel(const float* __restrict__ x,
                                                const float* __restrict__ proj,
                                                const float* __restrict__ bo,
                                                const float* __restrict__ gamma,
                                                const float* __restrict__ beta,
                                                float* __restrict__ out) {
  int row = blockIdx.x;
  int lane = threadIdx.x;
  size_t base = (size_t)row * D + lane * 4;
  float4 xv = *(const float4*)(x + base);
  float4 pv = *(const float4*)(proj + base);
  float4 bv = *(const float4*)(bo + lane * 4);
  float u0 = xv.x + pv.x + bv.x, u1 = xv.y + pv.y + bv.y;
  float u2 = xv.z + pv.z + bv.z, u3 = xv.w + pv.w + bv.w;
  float s = u0 + u1 + u2 + u3;
  for (int off = 32; off; off >>= 1) s += __shfl_down(s, off);
  s = __shfl(s, 0);
  float mean = s * (1.0f / D);
  float d0 = u0 - mean, d1 = u1 - mean, d2 = u2 - mean, d3 = u3 - mean;
  float ss = d0 * d0 + d1 * d1 + d2 * d2 + d3 * d3;
  for (int off = 32; off; off >>= 1) ss += __shfl_down(ss, off);
  ss = __shfl(ss, 0);
  float rstd = rsqrtf(ss * (1.0f / D) + 1e-5f);
  float4 gv = *(const float4*)(gamma + lane * 4);
  float4 be = *(const float4*)(beta + lane * 4);
  float4 o;
  o.x = d0 * rstd * gv.x + be.x;
  o.y = d1 * rstd * gv.y + be.y;
  o.z = d2 * rstd * gv.z + be.z;
  o.w = d3 * rstd * gv.w + be.w;
  *(float4*)(out + base) = o;
}

// ---------------------------------------------------------------------------
// Launch.  Adaptive workspace:
//  BIG path (ws >= 83,132,416 B): all-4-batch sim in one dispatch
//    XsN [0,12.58M) | sim [12.58M,79.69M) | topk | mask | Wt (tail)
//  SMALL path (proven 43.3 MB): two 2-batch phases (round-2 layout)
//  Phases B/C reuse [0,33.6M) in both paths.
// ---------------------------------------------------------------------------
extern "C" void kernel_launch(void* const* d_in, const int* in_sizes, int n_in,
                              void* d_out, int out_size, void* d_ws, size_t ws_size,
                              hipStream_t stream) {
  const float* x     = (const float*)d_in[0];
  const float* Wq    = (const float*)d_in[1];
  const float* Wk    = (const float*)d_in[2];
  const float* Wv    = (const float*)d_in[3];
  const float* Wo    = (const float*)d_in[4];
  const float* bo    = (const float*)d_in[5];
  const float* gamma = (const float*)d_in[6];
  const float* beta  = (const float*)d_in[7];
  float* out = (float*)d_out;

  char* ws = (char*)d_ws;
  const int AMAP_SIM = PK6(0, 1, 0, 1, 0, 2);
  const int BMAP_SIM = PK6(0, 0, 1, 1, 2, 0);
  const int AMAP_2T  = PK3(0, 1, 0);
  const int BMAP_2T  = PK3(0, 0, 1);

  bool big = ws_size >= (size_t)83132416;
  int* topkb;
  unsigned* mask;
  bf16* Wt;
  if (big) {
    bf16* XsN  = (bf16*)(ws);
    float* sim = (float*)(ws + 12582912);
    topkb = (int*)(ws + 79691776);
    mask  = (unsigned*)(ws + 79986688);
    Wt    = (bf16*)(ws + 82083840);
    splitrows_kernel<<<BATCH * N, 64, 0, stream>>>(x, XsN, 768, 1, 1);
    gemm_bt_kernel<<<dim3(16, 16, 4), 256, 0, stream>>>(
        XsN, XsN, sim, 768, 768, N, 24, AMAP_SIM, BMAP_SIM,
        (long)N * 768, (long)N * 768, (long)N * N, 1);
    topk_kernel<<<BATCH * N, 64, 0, stream>>>(sim, topkb);
  } else {
    bf16* XsN  = (bf16*)(ws);
    float* sim = (float*)(ws + 6291456);
    topkb = (int*)(ws + 39845888);
    mask  = (unsigned*)(ws + 40140800);
    Wt    = (bf16*)(ws + 42237952);
    for (int half = 0; half < 2; ++half) {
      splitrows_kernel<<<2 * N, 64, 0, stream>>>(x + (size_t)half * 2 * N * D, XsN, 768, 1, 1);
      gemm_bt_kernel<<<dim3(16, 16, 2), 256, 0, stream>>>(
          XsN, XsN, sim, 768, 768, N, 24, AMAP_SIM, BMAP_SIM,
          (long)N * 768, (long)N * 768, (long)N * N, 1);
      topk_kernel<<<2 * N, 64, 0, stream>>>(sim, topkb + (size_t)half * 2 * N * TOPK);
    }
  }
  (void)hipMemsetAsync(mask, 0, (size_t)BATCH * N * (N / 32) * sizeof(unsigned), stream);
  adj_kernel<<<(BATCH * N * TOPK + 255) / 256, 256, 0, stream>>>(topkb, mask);

  bf16* XsRaw = (bf16*)(ws);                 // 8,388,608
  float* qkv  = (float*)(ws + 8388608);      // 25,165,824
  splitrows_kernel<<<BATCH * N, 64, 0, stream>>>(x, XsRaw, 512, 0, 0);
  wsplit_kernel<<<1024, 64, 0, stream>>>(Wq, Wk, Wv, Wo, Wt);
  gemm_bt_kernel<<<dim3(6, 64, 1), 256, 0, stream>>>(
      XsRaw, Wt, qkv, 512, 512, 768, 12, AMAP_2T, BMAP_2T, 0, 0, 0, 0);

  float* ao = (float*)(ws);
  attn_kernel<<<(BATCH * N) / 4, 256, 0, stream>>>(qkv, mask, ao);

  bf16* aos   = (bf16*)(ws + 8388608);
  float* proj = (float*)(ws + 16777216);
  splitrows_kernel<<<BATCH * N, 64, 0, stream>>>(ao, aos, 512, 0, 0);
  gemm_bt_kernel<<<dim3(2, 64, 1), 256, 0, stream>>>(
      aos, Wt + (size_t)768 * 512, proj, 512, 512, D, 12, AMAP_2T, BMAP_2T, 0, 0, 0, 0);
  ln_kernel<<<BATCH * N, 64, 0, stream>>>(x, proj, bo, gamma, beta, out);
}